// Round 6
// baseline (2619.044 us; speedup 1.0000x reference)
//
#include <hip/hip_runtime.h>
#include <cstdint>
#include <cstddef>

#define D_MODEL 1024
#define D_STATE 16
#define E_DIM   2048
#define SEQ     4096
#define M_ROWS  16384

typedef unsigned short u16;
typedef unsigned int   u32;
typedef __attribute__((ext_vector_type(8))) short short8;   // 8 bf16 = 4 VGPRs
typedef __attribute__((ext_vector_type(4))) float f32x4;

__device__ __forceinline__ u16 f2bf(float f) {
    u32 u = __float_as_uint(f);
    u32 r = (u + 0x7fffu + ((u >> 16) & 1u)) >> 16;   // RNE
    return (u16)r;
}
__device__ __forceinline__ float bf2f(u16 h) {
    return __uint_as_float(((u32)h) << 16);
}

// async global->LDS, 16 B per lane. LDS dest is wave-uniform base + lane*16.
__device__ __forceinline__ void gld_lds16(const void* g, void* l) {
    __builtin_amdgcn_global_load_lds(
        (__attribute__((address_space(1))) void*)(uintptr_t)g,
        (__attribute__((address_space(3))) void*)(uintptr_t)l,
        16, 0, 0);
}

// ---------------------------------------------------------------------------
// PACKED TILE LAYOUT: every GEMM operand is stored as fragment-linear 128x64
// bf16 tiles (8192 u16). Chunk c (0..1023, 16 B each): msub=c>>7,
// step=(c>>6)&1, ell=c&63 -> row = msub*16+(ell&15),
// cols = (step*4 + (ell>>4))*8 .. +7.  Staging global reads are then fully
// linear (wave reads contiguous 1 KB) AND the LDS image is fragment-ordered,
// so frag ds_read_b128 = uniform base + lane*16 (conflict-free, per R5).
// Tile (Mt, Kt) of an [M, K] operand lives at ((Mt*(K/64) + Kt) * 8192).
// ---------------------------------------------------------------------------
#define BM 128
#define BN 128
#define HC_STR 17   // padded float stride for epilogue H/C tiles

// packed elementwise offset for XCp (K-dim = E_DIM = 2048, 32 k-tiles)
__device__ __forceinline__ size_t xcp_off(int m, int n) {
    int Mt = m >> 7, mr = m & 127;
    int Kt = n >> 6, nt = n & 63;
    int c16 = nt >> 3;
    int c = (mr >> 4) * 128 + (c16 >> 2) * 64 + (c16 & 3) * 16 + (mr & 15);
    return ((size_t)Mt * 32 + Kt) * 8192 + (size_t)c * 8 + (nt & 7);
}

union __align__(16) SMem {
    struct { u16 A[BM * 64]; u16 B[BN * 64]; } s;              // 16K + 16K
    struct { float H[BM * HC_STR]; float C[BN * HC_STR]; } e;  // 8.7K + 8.7K
};

// ---------------------------------------------------------------------------
// MFMA GEMM on packed operands. C[M,N] = A[M,K] @ B[N,K]^T.
// 128x128 tile, BK=64, 4 waves (2x2 of 64x64), 4x4 16x16x32 MFMA per wave.
// XCD swizzle: L%8 ~ XCD; XCD x owns m-strip x*(NY/8).., sweeps n within it
// so A-tiles stay L2-resident across their n-uses (R5 FETCH was 5.5x A).
// MODE 0: out bf16 row-major = acc + bias   (-> XP)
// MODE 1: gate: XCp <- sigmoid(acc+bias) * (H@C^T + Dp*XCp), packed in-place
// MODE 2: out fp32 row-major = acc + bias   (-> final out)
// ---------------------------------------------------------------------------
template <int MODE>
__global__ __launch_bounds__(256)
void mfma_gemm(const u16* __restrict__ Ag, const u16* __restrict__ Bg,
               int K, int Nst,
               const float* __restrict__ bias,
               u16* __restrict__ outb, float* __restrict__ outf,
               const float* __restrict__ Hm, const float* __restrict__ Cm,
               const float* __restrict__ Dp, u16* __restrict__ XCp)
{
    __shared__ SMem sm;
    const int t     = threadIdx.x;
    const int lane  = t & 63;
    const int w     = t >> 6;
    const int col_l = lane & 15;
    const int quad  = lane >> 4;
    const int wm = (w & 1) * 64;
    const int wn = (w >> 1) * 64;

    // XCD-aware swizzle (block->XCD ~ L%8): XCD owns contiguous m-strip.
    const int L = blockIdx.y * gridDim.x + blockIdx.x;
    const int xcd = L & 7, g = L >> 3;
    const int ntile = g % gridDim.x;
    const int mtile = xcd * (gridDim.y >> 3) + g / gridDim.x;
    const int bm = mtile * BM;
    const int bn = ntile * BN;

    const int KT = K >> 6;
    const u16* Abase = Ag + (size_t)mtile * KT * 8192;
    const u16* Bbase = Bg + (size_t)ntile * KT * 8192;

    f32x4 acc[4][4] = {};

    for (int kt = 0; kt < KT; ++kt) {
        const u16* at = Abase + (size_t)kt * 8192;
        const u16* bt = Bbase + (size_t)kt * 8192;
#pragma unroll
        for (int i = 0; i < 4; ++i)
            gld_lds16(at + (i * 256 + t) * 8, &sm.s.A[(i * 256 + t) * 8]);
#pragma unroll
        for (int i = 0; i < 4; ++i)
            gld_lds16(bt + (i * 256 + t) * 8, &sm.s.B[(i * 256 + t) * 8]);
        __syncthreads();

#pragma unroll
        for (int step = 0; step < 2; ++step) {   // two K=32 MFMA steps
            short8 af[4], bfr[4];
#pragma unroll
            for (int i = 0; i < 4; ++i) {
                int msub = (w & 1) * 4 + i;
                af[i] = *(const short8*)&sm.s.A[((msub * 2 + step) * 64 + lane) * 8];
            }
#pragma unroll
            for (int j = 0; j < 4; ++j) {
                int nsub = (w >> 1) * 4 + j;
                bfr[j] = *(const short8*)&sm.s.B[((nsub * 2 + step) * 64 + lane) * 8];
            }
#pragma unroll
            for (int i = 0; i < 4; ++i)
#pragma unroll
                for (int j = 0; j < 4; ++j)
                    acc[i][j] = __builtin_amdgcn_mfma_f32_16x16x32_bf16(
                        af[i], bfr[j], acc[i][j], 0, 0, 0);
        }
        __syncthreads();
    }

    // C/D layout: col = lane&15, row = quad*4 + reg   [verified m89/m91]
    if (MODE == 0) {
#pragma unroll
        for (int j = 0; j < 4; ++j) {
            int n = bn + wn + j * 16 + col_l;
            float bv = bias[n];
#pragma unroll
            for (int i = 0; i < 4; ++i) {
                int mb = bm + wm + i * 16 + quad * 4;
#pragma unroll
                for (int p = 0; p < 4; ++p)
                    outb[(size_t)(mb + p) * Nst + n] = f2bf(acc[i][j][p] + bv);
            }
        }
    } else if (MODE == 1) {
        for (int idx = t; idx < BM * D_STATE; idx += 256)
            sm.e.H[(idx >> 4) * HC_STR + (idx & 15)] =
                Hm[(size_t)(bm + (idx >> 4)) * D_STATE + (idx & 15)];
        for (int idx = t; idx < BN * D_STATE; idx += 256)
            sm.e.C[(idx >> 4) * HC_STR + (idx & 15)] =
                Cm[(size_t)(bn + (idx >> 4)) * D_STATE + (idx & 15)];
        __syncthreads();
#pragma unroll
        for (int i = 0; i < 4; ++i) {
            int ml = wm + i * 16 + quad * 4;
#pragma unroll
            for (int p = 0; p < 4; ++p) {
                float hrow[D_STATE];
#pragma unroll
                for (int s = 0; s < D_STATE; ++s)
                    hrow[s] = sm.e.H[(ml + p) * HC_STR + s];
#pragma unroll
                for (int j = 0; j < 4; ++j) {
                    int nl = wn + j * 16 + col_l;
                    int n = bn + nl;
                    float z = acc[i][j][p] + bias[n];
                    float sig = 1.f / (1.f + __expf(-z));
                    float dot = 0.f;
#pragma unroll
                    for (int s = 0; s < D_STATE; ++s)
                        dot += hrow[s] * sm.e.C[nl * HC_STR + s];
                    // packed in-place RMW: read & write the SAME address
                    size_t off = xcp_off(bm + ml + p, n);
                    float xc = bf2f(XCp[off]);
                    XCp[off] = f2bf(sig * (dot + Dp[n] * xc));
                }
            }
        }
    } else {
#pragma unroll
        for (int j = 0; j < 4; ++j) {
            int n = bn + wn + j * 16 + col_l;
            float bv = bias[n];
#pragma unroll
            for (int i = 0; i < 4; ++i) {
                int mb = bm + wm + i * 16 + quad * 4;
#pragma unroll
                for (int p = 0; p < 4; ++p)
                    outf[(size_t)(mb + p) * Nst + n] = acc[i][j][p] + bv;
            }
        }
    }
}

// ---------------------------------------------------------------------------
// pack x fp32 [16384,1024] -> packed bf16 tiles (K-dim 1024, 16 k-tiles)
// ---------------------------------------------------------------------------
__global__ __launch_bounds__(256)
void pack_x_kernel(const float* __restrict__ x, u16* __restrict__ xp)
{
    const int Kt = blockIdx.x;   // 0..15
    const int Mt = blockIdx.y;   // 0..127
    const int t  = threadIdx.x;
    u16* dst = xp + ((size_t)Mt * 16 + Kt) * 8192;
#pragma unroll
    for (int i = 0; i < 4; ++i) {
        int c   = i * 256 + t;
        int ell = c & 63;
        int row = Mt * 128 + (c >> 7) * 16 + (ell & 15);
        int col = Kt * 64 + (((c >> 6) & 1) * 4 + (ell >> 4)) * 8;
        const float4* src = (const float4*)&x[(size_t)row * D_MODEL + col];
        float4 a = src[0], b = src[1];
        alignas(16) u16 o[8] = {f2bf(a.x), f2bf(a.y), f2bf(a.z), f2bf(a.w),
                                f2bf(b.x), f2bf(b.y), f2bf(b.z), f2bf(b.w)};
        *(short8*)(dst + c * 8) = *(const short8*)o;
    }
}

// ---------------------------------------------------------------------------
// pack W^T: src W [K, Wstride] fp32 (cols colOff..colOff+Nt*128) -> packed
// bf16 tiles of B = W^T [N, K].
// ---------------------------------------------------------------------------
__global__ __launch_bounds__(256)
void pack_w_kernel(const float* __restrict__ W, u16* __restrict__ out,
                   int Wstride, int colOff, int KT)
{
    const int Kt = blockIdx.x;
    const int Nt = blockIdx.y;
    const int t  = threadIdx.x;
    u16* dst = out + ((size_t)Nt * KT + Kt) * 8192;
#pragma unroll
    for (int i = 0; i < 4; ++i) {
        int c    = i * 256 + t;
        int ell  = c & 63;
        int nrow = Nt * 128 + (c >> 7) * 16 + (ell & 15);
        int kcol = Kt * 64 + (((c >> 6) & 1) * 4 + (ell >> 4)) * 8;
        alignas(16) u16 o[8];
#pragma unroll
        for (int q = 0; q < 8; ++q)
            o[q] = f2bf(W[(size_t)(kcol + q) * Wstride + colOff + nrow]);
        *(short8*)(dst + c * 8) = *(const short8*)o;
    }
}

// ---------------------------------------------------------------------------
// causal depthwise conv (taps=4): XP row-major bf16 -> XCp PACKED bf16.
// block per (k-tile, m-tile); writes are fully linear per tile.
// ---------------------------------------------------------------------------
__global__ __launch_bounds__(256)
void conv_kernel(const u16* __restrict__ XP, const float* __restrict__ conv_w,
                 const float* __restrict__ conv_b, u16* __restrict__ XCp)
{
    const int Kt = blockIdx.x;   // 0..31
    const int Mt = blockIdx.y;   // 0..127
    const int t  = threadIdx.x;
    u16* dst = XCp + ((size_t)Mt * 32 + Kt) * 8192;
#pragma unroll
    for (int i = 0; i < 4; ++i) {
        int c   = i * 256 + t;
        int ell = c & 63;
        int mr  = (c >> 7) * 16 + (ell & 15);
        int e   = Kt * 64 + (((c >> 6) & 1) * 4 + (ell >> 4)) * 8;
        int m   = Mt * 128 + mr;
        int l   = m & (SEQ - 1);
        float acc[8];
        {
            float4 c0 = *(const float4*)&conv_b[e];
            float4 c1 = *(const float4*)&conv_b[e + 4];
            acc[0] = c0.x; acc[1] = c0.y; acc[2] = c0.z; acc[3] = c0.w;
            acc[4] = c1.x; acc[5] = c1.y; acc[6] = c1.z; acc[7] = c1.w;
        }
#pragma unroll
        for (int k = 0; k < 4; ++k) {
            if (l - 3 + k >= 0) {
                const short8 xv = *(const short8*)&XP[(size_t)(m - 3 + k) * E_DIM + e];
#pragma unroll
                for (int j = 0; j < 8; ++j)
                    acc[j] += bf2f((u16)xv[j]) * conv_w[(size_t)(e + j) * 4 + k];
            }
        }
        alignas(16) u16 o[8];
#pragma unroll
        for (int j = 0; j < 8; ++j) o[j] = f2bf(acc[j]);
        *(short8*)(dst + c * 8) = *(const short8*)o;
    }
}

// ---------------------------------------------------------------------------
// U[m,s] = sum_e XCp[m,e] * A[e,s]  (fp32 acc; reads packed XCp)
// ---------------------------------------------------------------------------
__global__ __launch_bounds__(256)
void u_kernel(const u16* __restrict__ XCp, const float* __restrict__ Amat,
              float* __restrict__ U)
{
    __shared__ float part[(256 + 16) * HC_STR];
    const int m = blockIdx.x, t = threadIdx.x;
    const int Mt = m >> 7, mr = m & 127;
    const int Kt = t >> 3, c16 = t & 7;
    const int e0 = Kt * 64 + c16 * 8;
    const int c  = (mr >> 4) * 128 + (c16 >> 2) * 64 + (c16 & 3) * 16 + (mr & 15);
    const short8 xv = *(const short8*)&XCp[((size_t)Mt * 32 + Kt) * 8192 + (size_t)c * 8];

    float acc[16];
#pragma unroll
    for (int s = 0; s < 16; ++s) acc[s] = 0.f;
#pragma unroll
    for (int q = 0; q < 8; ++q) {
        float xq = bf2f((u16)xv[q]);
        const float4* ar = (const float4*)&Amat[(size_t)(e0 + q) * D_STATE];
#pragma unroll
        for (int s4 = 0; s4 < 4; ++s4) {
            float4 a = ar[s4];
            acc[s4 * 4 + 0] += xq * a.x; acc[s4 * 4 + 1] += xq * a.y;
            acc[s4 * 4 + 2] += xq * a.z; acc[s4 * 4 + 3] += xq * a.w;
        }
    }
#pragma unroll
    for (int s = 0; s < 16; ++s) part[t * HC_STR + s] = acc[s];
    __syncthreads();
    {
        int s = t & 15, grp = t >> 4;
        float sum = 0.f;
#pragma unroll
        for (int r = 0; r < 16; ++r) sum += part[(grp + r * 16) * HC_STR + s];
        part[(256 + grp) * HC_STR + s] = sum;
    }
    __syncthreads();
    if (t < 16) {
        float sum = 0.f;
#pragma unroll
        for (int g2 = 0; g2 < 16; ++g2) sum += part[(256 + g2) * HC_STR + t];
        U[(size_t)m * D_STATE + t] = sum;
    }
}

// ---------------------------------------------------------------------------
// sequential scan: h_l = tanh(U_l + h_{l-1}), 64 chains, 8-deep prefetch ring
// ---------------------------------------------------------------------------
__global__ __launch_bounds__(64)
void scan_kernel(const float* __restrict__ U, float* __restrict__ H)
{
    const int t = threadIdx.x;
    const int b = t >> 4;
    const int s = t & 15;
    const float* u = U + (size_t)b * SEQ * D_STATE + s;
    float*       h = H + (size_t)b * SEQ * D_STATE + s;

    float buf[8];
#pragma unroll
    for (int j = 0; j < 8; ++j) buf[j] = u[(size_t)j * D_STATE];
    float hv = 0.f;
    for (int l = 0; l < SEQ; ++l) {
        float ucur = buf[l & 7];
        if (l + 8 < SEQ) buf[l & 7] = u[(size_t)(l + 8) * D_STATE];
        float ex = __expf(2.f * (ucur + hv));
        hv = 1.f - 2.f / (ex + 1.f);
        h[(size_t)l * D_STATE] = hv;
    }
}

// ---------------------------------------------------------------------------
extern "C" void kernel_launch(void* const* d_in, const int* in_sizes, int n_in,
                              void* d_out, int out_size, void* d_ws, size_t ws_size,
                              hipStream_t stream)
{
    const float* x      = (const float*)d_in[0];
    const float* W_in   = (const float*)d_in[1];
    const float* b_in   = (const float*)d_in[2];
    const float* conv_w = (const float*)d_in[3];
    const float* conv_b = (const float*)d_in[4];
    const float* Amat   = (const float*)d_in[5];
    const float* Cmat   = (const float*)d_in[6];
    const float* Dp     = (const float*)d_in[7];
    const float* W_out  = (const float*)d_in[8];
    const float* b_out  = (const float*)d_in[9];
    float* out = (float*)d_out;

    // workspace layout (115.3 MB total; 136 MB proven safe)
    char* ws = (char*)d_ws;
    u16*   xbp  = (u16*)(ws);                    // 33.55 MB packed x
    u16*   Wp0  = (u16*)(ws +  33554432);        //  4.19 MB packed W_in[:, :2048]^T
    u16*   Wp1  = (u16*)(ws +  37748736);        //  4.19 MB packed W_in[:, 2048:]^T
    u16*   Wp2  = (u16*)(ws +  41943040);        //  4.19 MB packed W_out^T
    u16*   XCp  = (u16*)(ws +  46137344);        // 67.11 MB packed x_conv
    float* U    = (float*)(ws + 113246208);      //  1.05 MB
    float* H    = (float*)(ws + 114294784);      //  1.05 MB
    u16*   XP   = (u16*)d_out;  // x_proj bf16 in d_out (67.1 MB), dead after conv

    // 1) pack inputs
    pack_x_kernel<<<dim3(16, 128), 256, 0, stream>>>(x, xbp);
    pack_w_kernel<<<dim3(16, 16), 256, 0, stream>>>(W_in, Wp0, 2 * E_DIM, 0, 16);
    pack_w_kernel<<<dim3(16, 16), 256, 0, stream>>>(W_in, Wp1, 2 * E_DIM, E_DIM, 16);
    pack_w_kernel<<<dim3(32, 8), 256, 0, stream>>>(W_out, Wp2, D_MODEL, 0, 32);

    // 2) XP = bf16(x @ W_in[:, :2048] + b_in)   (row-major, -> d_out)
    mfma_gemm<0><<<dim3(16, 128), 256, 0, stream>>>(
        xbp, Wp0, D_MODEL, E_DIM, b_in, XP, nullptr, nullptr, nullptr, nullptr, nullptr);

    // 3) XCp = packed bf16(causal_conv(XP) + conv_b)
    conv_kernel<<<dim3(32, 128), 256, 0, stream>>>(XP, conv_w, conv_b, XCp);

    // 4) U = XC @ A ; 5) scan -> H
    u_kernel<<<M_ROWS, 256, 0, stream>>>(XCp, Amat, U);
    scan_kernel<<<1, 64, 0, stream>>>(U, H);

    // 6) XCp <- sigmoid(x @ W_in[:, 2048:] + b_in[2048:]) * (H@C^T + Dp*XCp)
    mfma_gemm<1><<<dim3(16, 128), 256, 0, stream>>>(
        xbp, Wp1, D_MODEL, 0, b_in + E_DIM, nullptr, nullptr, H, Cmat, Dp, XCp);

    // 7) out = XC @ W_out + b_out   (fp32, row-major)
    mfma_gemm<2><<<dim3(8, 128), 256, 0, stream>>>(
        XCp, Wp2, E_DIM, D_MODEL, b_out, nullptr, out, nullptr, nullptr, nullptr, nullptr);
}

// Round 7
// 1469.266 us; speedup vs baseline: 1.7826x; 1.7826x over previous
//
#include <hip/hip_runtime.h>
#include <cstdint>
#include <cstddef>

#define D_MODEL 1024
#define D_STATE 16
#define E_DIM   2048
#define SEQ     4096
#define M_ROWS  16384

typedef unsigned short u16;
typedef unsigned int   u32;
typedef __attribute__((ext_vector_type(8))) short short8;   // 8 bf16 = 4 VGPRs
typedef __attribute__((ext_vector_type(4))) float f32x4;

__device__ __forceinline__ u16 f2bf(float f) {
    u32 u = __float_as_uint(f);
    u32 r = (u + 0x7fffu + ((u >> 16) & 1u)) >> 16;   // RNE
    return (u16)r;
}
__device__ __forceinline__ float bf2f(u16 h) {
    return __uint_as_float(((u32)h) << 16);
}

// async global->LDS, 16 B per lane. LDS dest is wave-uniform base + lane*16.
__device__ __forceinline__ void gld_lds16(const void* g, void* l) {
    __builtin_amdgcn_global_load_lds(
        (__attribute__((address_space(1))) void*)(uintptr_t)g,
        (__attribute__((address_space(3))) void*)(uintptr_t)l,
        16, 0, 0);
}

// ---------------------------------------------------------------------------
// PACKED TILE LAYOUT: every GEMM operand is stored as fragment-linear 128x64
// bf16 tiles (8192 u16). Chunk c (0..1023, 16 B each): msub=c>>7,
// step=(c>>6)&1, ell=c&63 -> row = msub*16+(ell&15),
// cols = (step*4 + (ell>>4))*8 .. +7.  Staging global reads are then fully
// linear (wave reads contiguous 1 KB) AND the LDS image is fragment-ordered,
// so frag ds_read_b128 = uniform base + lane*16 (conflict-free, per R5).
// Tile (Mt, Kt) of an [M, K] operand lives at ((Mt*(K/64) + Kt) * 8192).
// ---------------------------------------------------------------------------
#define BM 128
#define BN 128
#define HC_STR 17   // padded float stride for epilogue H/C tiles

// packed elementwise offset for XCp (K-dim = E_DIM = 2048, 32 k-tiles)
__device__ __forceinline__ size_t xcp_off(int m, int n) {
    int Mt = m >> 7, mr = m & 127;
    int Kt = n >> 6, nt = n & 63;
    int c16 = nt >> 3;
    int c = (mr >> 4) * 128 + (c16 >> 2) * 64 + (c16 & 3) * 16 + (mr & 15);
    return ((size_t)Mt * 32 + Kt) * 8192 + (size_t)c * 8 + (nt & 7);
}

union __align__(16) SMem {
    struct { u16 A[BM * 64]; u16 B[BN * 64]; } s;              // 16K + 16K
    struct { float H[BM * HC_STR]; float C[BN * HC_STR]; } e;  // 8.7K + 8.7K
};

// ---------------------------------------------------------------------------
// MFMA GEMM on packed operands. C[M,N] = A[M,K] @ B[N,K]^T.
// 128x128 tile, BK=64, 4 waves (2x2 of 64x64), 4x4 16x16x32 MFMA per wave.
// XCD swizzle: L%8 ~ XCD; XCD x owns m-strip x*(NY/8).., sweeps n within it
// so A-tiles stay L2-resident across their n-uses (R5 FETCH was 5.5x A).
// MODE 0: out bf16 row-major = acc + bias   (-> XP)
// MODE 1: gate: XCp <- sigmoid(acc+bias) * (H@C^T + Dp*XCp), packed in-place
// MODE 2: out fp32 row-major = acc + bias   (-> final out)
// ---------------------------------------------------------------------------
template <int MODE>
__global__ __launch_bounds__(256)
void mfma_gemm(const u16* __restrict__ Ag, const u16* __restrict__ Bg,
               int K, int Nst,
               const float* __restrict__ bias,
               u16* __restrict__ outb, float* __restrict__ outf,
               const float* __restrict__ Hm, const float* __restrict__ Cm,
               const float* __restrict__ Dp, u16* __restrict__ XCp)
{
    __shared__ SMem sm;
    const int t     = threadIdx.x;
    const int lane  = t & 63;
    const int w     = t >> 6;
    const int col_l = lane & 15;
    const int quad  = lane >> 4;
    const int wm = (w & 1) * 64;
    const int wn = (w >> 1) * 64;

    // XCD-aware swizzle (block->XCD ~ L%8): XCD owns contiguous m-strip.
    const int L = blockIdx.y * gridDim.x + blockIdx.x;
    const int xcd = L & 7, g = L >> 3;
    const int ntile = g % gridDim.x;
    const int mtile = xcd * (gridDim.y >> 3) + g / gridDim.x;
    const int bm = mtile * BM;
    const int bn = ntile * BN;

    const int KT = K >> 6;
    const u16* Abase = Ag + (size_t)mtile * KT * 8192;
    const u16* Bbase = Bg + (size_t)ntile * KT * 8192;

    f32x4 acc[4][4] = {};

    for (int kt = 0; kt < KT; ++kt) {
        const u16* at = Abase + (size_t)kt * 8192;
        const u16* bt = Bbase + (size_t)kt * 8192;
#pragma unroll
        for (int i = 0; i < 4; ++i)
            gld_lds16(at + (i * 256 + t) * 8, &sm.s.A[(i * 256 + t) * 8]);
#pragma unroll
        for (int i = 0; i < 4; ++i)
            gld_lds16(bt + (i * 256 + t) * 8, &sm.s.B[(i * 256 + t) * 8]);
        __syncthreads();

#pragma unroll
        for (int step = 0; step < 2; ++step) {   // two K=32 MFMA steps
            short8 af[4], bfr[4];
#pragma unroll
            for (int i = 0; i < 4; ++i) {
                int msub = (w & 1) * 4 + i;
                af[i] = *(const short8*)&sm.s.A[((msub * 2 + step) * 64 + lane) * 8];
            }
#pragma unroll
            for (int j = 0; j < 4; ++j) {
                int nsub = (w >> 1) * 4 + j;
                bfr[j] = *(const short8*)&sm.s.B[((nsub * 2 + step) * 64 + lane) * 8];
            }
#pragma unroll
            for (int i = 0; i < 4; ++i)
#pragma unroll
                for (int j = 0; j < 4; ++j)
                    acc[i][j] = __builtin_amdgcn_mfma_f32_16x16x32_bf16(
                        af[i], bfr[j], acc[i][j], 0, 0, 0);
        }
        __syncthreads();
    }

    // C/D layout: col = lane&15, row = quad*4 + reg   [verified m89/m91]
    if (MODE == 0) {
#pragma unroll
        for (int j = 0; j < 4; ++j) {
            int n = bn + wn + j * 16 + col_l;
            float bv = bias[n];
#pragma unroll
            for (int i = 0; i < 4; ++i) {
                int mb = bm + wm + i * 16 + quad * 4;
#pragma unroll
                for (int p = 0; p < 4; ++p)
                    outb[(size_t)(mb + p) * Nst + n] = f2bf(acc[i][j][p] + bv);
            }
        }
    } else if (MODE == 1) {
        for (int idx = t; idx < BM * D_STATE; idx += 256)
            sm.e.H[(idx >> 4) * HC_STR + (idx & 15)] =
                Hm[(size_t)(bm + (idx >> 4)) * D_STATE + (idx & 15)];
        for (int idx = t; idx < BN * D_STATE; idx += 256)
            sm.e.C[(idx >> 4) * HC_STR + (idx & 15)] =
                Cm[(size_t)(bn + (idx >> 4)) * D_STATE + (idx & 15)];
        __syncthreads();
#pragma unroll
        for (int i = 0; i < 4; ++i) {
            int ml = wm + i * 16 + quad * 4;
#pragma unroll
            for (int p = 0; p < 4; ++p) {
                float hrow[D_STATE];
#pragma unroll
                for (int s = 0; s < D_STATE; ++s)
                    hrow[s] = sm.e.H[(ml + p) * HC_STR + s];
#pragma unroll
                for (int j = 0; j < 4; ++j) {
                    int nl = wn + j * 16 + col_l;
                    int n = bn + nl;
                    float z = acc[i][j][p] + bias[n];
                    float sig = 1.f / (1.f + __expf(-z));
                    float dot = 0.f;
#pragma unroll
                    for (int s = 0; s < D_STATE; ++s)
                        dot += hrow[s] * sm.e.C[nl * HC_STR + s];
                    // packed in-place RMW: read & write the SAME address
                    size_t off = xcp_off(bm + ml + p, n);
                    float xc = bf2f(XCp[off]);
                    XCp[off] = f2bf(sig * (dot + Dp[n] * xc));
                }
            }
        }
    } else {
#pragma unroll
        for (int j = 0; j < 4; ++j) {
            int n = bn + wn + j * 16 + col_l;
            float bv = bias[n];
#pragma unroll
            for (int i = 0; i < 4; ++i) {
                int mb = bm + wm + i * 16 + quad * 4;
#pragma unroll
                for (int p = 0; p < 4; ++p)
                    outf[(size_t)(mb + p) * Nst + n] = acc[i][j][p] + bv;
            }
        }
    }
}

// ---------------------------------------------------------------------------
// pack x fp32 [16384,1024] -> packed bf16 tiles (K-dim 1024, 16 k-tiles)
// ---------------------------------------------------------------------------
__global__ __launch_bounds__(256)
void pack_x_kernel(const float* __restrict__ x, u16* __restrict__ xp)
{
    const int Kt = blockIdx.x;   // 0..15
    const int Mt = blockIdx.y;   // 0..127
    const int t  = threadIdx.x;
    u16* dst = xp + ((size_t)Mt * 16 + Kt) * 8192;
#pragma unroll
    for (int i = 0; i < 4; ++i) {
        int c   = i * 256 + t;
        int ell = c & 63;
        int row = Mt * 128 + (c >> 7) * 16 + (ell & 15);
        int col = Kt * 64 + (((c >> 6) & 1) * 4 + (ell >> 4)) * 8;
        const float4* src = (const float4*)&x[(size_t)row * D_MODEL + col];
        float4 a = src[0], b = src[1];
        alignas(16) u16 o[8] = {f2bf(a.x), f2bf(a.y), f2bf(a.z), f2bf(a.w),
                                f2bf(b.x), f2bf(b.y), f2bf(b.z), f2bf(b.w)};
        *(short8*)(dst + c * 8) = *(const short8*)o;
    }
}

// ---------------------------------------------------------------------------
// pack W^T: src W [K, Wstride] fp32 (cols colOff..colOff+Nt*128) -> packed
// bf16 tiles of B = W^T [N, K].
// ---------------------------------------------------------------------------
__global__ __launch_bounds__(256)
void pack_w_kernel(const float* __restrict__ W, u16* __restrict__ out,
                   int Wstride, int colOff, int KT)
{
    const int Kt = blockIdx.x;
    const int Nt = blockIdx.y;
    const int t  = threadIdx.x;
    u16* dst = out + ((size_t)Nt * KT + Kt) * 8192;
#pragma unroll
    for (int i = 0; i < 4; ++i) {
        int c    = i * 256 + t;
        int ell  = c & 63;
        int nrow = Nt * 128 + (c >> 7) * 16 + (ell & 15);
        int kcol = Kt * 64 + (((c >> 6) & 1) * 4 + (ell >> 4)) * 8;
        alignas(16) u16 o[8];
#pragma unroll
        for (int q = 0; q < 8; ++q)
            o[q] = f2bf(W[(size_t)(kcol + q) * Wstride + colOff + nrow]);
        *(short8*)(dst + c * 8) = *(const short8*)o;
    }
}

// ---------------------------------------------------------------------------
// causal depthwise conv (taps=4): XP row-major bf16 -> XCp PACKED bf16.
// block per (k-tile, m-tile); writes are fully linear per tile.
// ---------------------------------------------------------------------------
__global__ __launch_bounds__(256)
void conv_kernel(const u16* __restrict__ XP, const float* __restrict__ conv_w,
                 const float* __restrict__ conv_b, u16* __restrict__ XCp)
{
    const int Kt = blockIdx.x;   // 0..31
    const int Mt = blockIdx.y;   // 0..127
    const int t  = threadIdx.x;
    u16* dst = XCp + ((size_t)Mt * 32 + Kt) * 8192;
#pragma unroll
    for (int i = 0; i < 4; ++i) {
        int c   = i * 256 + t;
        int ell = c & 63;
        int mr  = (c >> 7) * 16 + (ell & 15);
        int e   = Kt * 64 + (((c >> 6) & 1) * 4 + (ell >> 4)) * 8;
        int m   = Mt * 128 + mr;
        int l   = m & (SEQ - 1);
        float acc[8];
        {
            float4 c0 = *(const float4*)&conv_b[e];
            float4 c1 = *(const float4*)&conv_b[e + 4];
            acc[0] = c0.x; acc[1] = c0.y; acc[2] = c0.z; acc[3] = c0.w;
            acc[4] = c1.x; acc[5] = c1.y; acc[6] = c1.z; acc[7] = c1.w;
        }
#pragma unroll
        for (int k = 0; k < 4; ++k) {
            if (l - 3 + k >= 0) {
                const short8 xv = *(const short8*)&XP[(size_t)(m - 3 + k) * E_DIM + e];
#pragma unroll
                for (int j = 0; j < 8; ++j)
                    acc[j] += bf2f((u16)xv[j]) * conv_w[(size_t)(e + j) * 4 + k];
            }
        }
        alignas(16) u16 o[8];
#pragma unroll
        for (int j = 0; j < 8; ++j) o[j] = f2bf(acc[j]);
        *(short8*)(dst + c * 8) = *(const short8*)o;
    }
}

// ---------------------------------------------------------------------------
// U[m,s] = sum_e XCp[m,e] * A[e,s]  (fp32 acc; reads packed XCp)
// ---------------------------------------------------------------------------
__global__ __launch_bounds__(256)
void u_kernel(const u16* __restrict__ XCp, const float* __restrict__ Amat,
              float* __restrict__ U)
{
    __shared__ float part[(256 + 16) * HC_STR];
    const int m = blockIdx.x, t = threadIdx.x;
    const int Mt = m >> 7, mr = m & 127;
    const int Kt = t >> 3, c16 = t & 7;
    const int e0 = Kt * 64 + c16 * 8;
    const int c  = (mr >> 4) * 128 + (c16 >> 2) * 64 + (c16 & 3) * 16 + (mr & 15);
    const short8 xv = *(const short8*)&XCp[((size_t)Mt * 32 + Kt) * 8192 + (size_t)c * 8];

    float acc[16];
#pragma unroll
    for (int s = 0; s < 16; ++s) acc[s] = 0.f;
#pragma unroll
    for (int q = 0; q < 8; ++q) {
        float xq = bf2f((u16)xv[q]);
        const float4* ar = (const float4*)&Amat[(size_t)(e0 + q) * D_STATE];
#pragma unroll
        for (int s4 = 0; s4 < 4; ++s4) {
            float4 a = ar[s4];
            acc[s4 * 4 + 0] += xq * a.x; acc[s4 * 4 + 1] += xq * a.y;
            acc[s4 * 4 + 2] += xq * a.z; acc[s4 * 4 + 3] += xq * a.w;
        }
    }
#pragma unroll
    for (int s = 0; s < 16; ++s) part[t * HC_STR + s] = acc[s];
    __syncthreads();
    {
        int s = t & 15, grp = t >> 4;
        float sum = 0.f;
#pragma unroll
        for (int r = 0; r < 16; ++r) sum += part[(grp + r * 16) * HC_STR + s];
        part[(256 + grp) * HC_STR + s] = sum;
    }
    __syncthreads();
    if (t < 16) {
        float sum = 0.f;
#pragma unroll
        for (int g2 = 0; g2 < 16; ++g2) sum += part[(256 + g2) * HC_STR + t];
        U[(size_t)m * D_STATE + t] = sum;
    }
}

// ---------------------------------------------------------------------------
// sequential scan: h_l = tanh(U_l + h_{l-1}), 64 chains.
// Chunked by 8 with FULLY-UNROLLED static-index arrays (stay in VGPRs --
// R6's dynamic ring index spilled to scratch: 1413 us, 830 cyc/iter).
// Next chunk's 8 independent loads issue before this chunk's ~290-cycle
// dependent tanh chain, covering L2/L3 latency.
// ---------------------------------------------------------------------------
__global__ __launch_bounds__(64)
void scan_kernel(const float* __restrict__ U, float* __restrict__ H)
{
    const int t = threadIdx.x;
    const int b = t >> 4;
    const int s = t & 15;
    const float* u = U + (size_t)b * SEQ * D_STATE + s;
    float*       h = H + (size_t)b * SEQ * D_STATE + s;

    float cur[8], nxt[8];
#pragma unroll
    for (int j = 0; j < 8; ++j) cur[j] = u[(size_t)j * D_STATE];

    float hv = 0.f;
    for (int l0 = 0; l0 < SEQ; l0 += 8) {
        if (l0 + 8 < SEQ) {
#pragma unroll
            for (int j = 0; j < 8; ++j)
                nxt[j] = u[(size_t)(l0 + 8 + j) * D_STATE];
        }
#pragma unroll
        for (int j = 0; j < 8; ++j) {
            float ex = __expf(2.f * (cur[j] + hv));
            hv = 1.f - 2.f / (ex + 1.f);
            h[(size_t)(l0 + j) * D_STATE] = hv;
        }
#pragma unroll
        for (int j = 0; j < 8; ++j) cur[j] = nxt[j];
    }
}

// ---------------------------------------------------------------------------
extern "C" void kernel_launch(void* const* d_in, const int* in_sizes, int n_in,
                              void* d_out, int out_size, void* d_ws, size_t ws_size,
                              hipStream_t stream)
{
    const float* x      = (const float*)d_in[0];
    const float* W_in   = (const float*)d_in[1];
    const float* b_in   = (const float*)d_in[2];
    const float* conv_w = (const float*)d_in[3];
    const float* conv_b = (const float*)d_in[4];
    const float* Amat   = (const float*)d_in[5];
    const float* Cmat   = (const float*)d_in[6];
    const float* Dp     = (const float*)d_in[7];
    const float* W_out  = (const float*)d_in[8];
    const float* b_out  = (const float*)d_in[9];
    float* out = (float*)d_out;

    // workspace layout (115.3 MB total; 136 MB proven safe)
    char* ws = (char*)d_ws;
    u16*   xbp  = (u16*)(ws);                    // 33.55 MB packed x
    u16*   Wp0  = (u16*)(ws +  33554432);        //  4.19 MB packed W_in[:, :2048]^T
    u16*   Wp1  = (u16*)(ws +  37748736);        //  4.19 MB packed W_in[:, 2048:]^T
    u16*   Wp2  = (u16*)(ws +  41943040);        //  4.19 MB packed W_out^T
    u16*   XCp  = (u16*)(ws +  46137344);        // 67.11 MB packed x_conv
    float* U    = (float*)(ws + 113246208);      //  1.05 MB
    float* H    = (float*)(ws + 114294784);      //  1.05 MB
    u16*   XP   = (u16*)d_out;  // x_proj bf16 in d_out (67.1 MB), dead after conv

    // 1) pack inputs
    pack_x_kernel<<<dim3(16, 128), 256, 0, stream>>>(x, xbp);
    pack_w_kernel<<<dim3(16, 16), 256, 0, stream>>>(W_in, Wp0, 2 * E_DIM, 0, 16);
    pack_w_kernel<<<dim3(16, 16), 256, 0, stream>>>(W_in, Wp1, 2 * E_DIM, E_DIM, 16);
    pack_w_kernel<<<dim3(32, 8), 256, 0, stream>>>(W_out, Wp2, D_MODEL, 0, 32);

    // 2) XP = bf16(x @ W_in[:, :2048] + b_in)   (row-major, -> d_out)
    mfma_gemm<0><<<dim3(16, 128), 256, 0, stream>>>(
        xbp, Wp0, D_MODEL, E_DIM, b_in, XP, nullptr, nullptr, nullptr, nullptr, nullptr);

    // 3) XCp = packed bf16(causal_conv(XP) + conv_b)
    conv_kernel<<<dim3(32, 128), 256, 0, stream>>>(XP, conv_w, conv_b, XCp);

    // 4) U = XC @ A ; 5) scan -> H
    u_kernel<<<M_ROWS, 256, 0, stream>>>(XCp, Amat, U);
    scan_kernel<<<1, 64, 0, stream>>>(U, H);

    // 6) XCp <- sigmoid(x @ W_in[:, 2048:] + b_in[2048:]) * (H@C^T + Dp*XCp)
    mfma_gemm<1><<<dim3(16, 128), 256, 0, stream>>>(
        xbp, Wp1, D_MODEL, 0, b_in + E_DIM, nullptr, nullptr, H, Cmat, Dp, XCp);

    // 7) out = XC @ W_out + b_out   (fp32, row-major)
    mfma_gemm<2><<<dim3(8, 128), 256, 0, stream>>>(
        XCp, Wp2, E_DIM, D_MODEL, b_out, nullptr, out, nullptr, nullptr, nullptr, nullptr);
}